// Round 1
// baseline (1146.492 us; speedup 1.0000x reference)
//
#include <hip/hip_runtime.h>

#define N_NODESC 100000
#define N_EDGESC 600000
#define E_TOTC   700000
#define NUM_GRAPHSC 512
#define NEG_SLOPE 0.2f
#define NEG_INF_ENC 0x007FFFFFu

// monotone float<->uint mapping so unsigned atomicMax == float max
__device__ __forceinline__ unsigned enc_f32(float f) {
    unsigned u = __float_as_uint(f);
    return (u & 0x80000000u) ? ~u : (u | 0x80000000u);
}
__device__ __forceinline__ float dec_f32(unsigned u) {
    u = (u & 0x80000000u) ? (u ^ 0x80000000u) : ~u;
    return __uint_as_float(u);
}

__global__ void fill_u32(unsigned* __restrict__ p, unsigned v, int n) {
    int i = blockIdx.x * blockDim.x + threadIdx.x;
    if (i < n) p[i] = v;
}

// Y[n,j] = sum_k X[n,k] * W[k,j];  K = 128 fixed. blockDim=(FOUT, 256/FOUT)
template <int FOUT, int NPT>
__global__ __launch_bounds__(256) void gemm_rm(const float* __restrict__ X,
                                               const float* __restrict__ W,
                                               float* __restrict__ Y, int N) {
    constexpr int K = 128;
    constexpr int NROWS = 256 / FOUT;
    constexpr int NPB = NROWS * NPT;
    __shared__ float xs[NPB][K];
    int tid = threadIdx.y * FOUT + threadIdx.x;
    size_t node0 = (size_t)blockIdx.x * NPB;
    const float4* Xv = (const float4*)(X + node0 * K);
    float4* xsv = (float4*)(&xs[0][0]);
#pragma unroll
    for (int i = 0; i < NPB * K / 4 / 256; ++i) xsv[tid + i * 256] = Xv[tid + i * 256];
    __syncthreads();
    int j = threadIdx.x;
    float acc[NPT];
#pragma unroll
    for (int r = 0; r < NPT; ++r) acc[r] = 0.f;
    const float* xrow = &xs[threadIdx.y * NPT][0];
#pragma unroll
    for (int k = 0; k < K; ++k) {
        float w = W[k * FOUT + j];
#pragma unroll
        for (int r = 0; r < NPT; ++r) acc[r] += xrow[r * K + k] * w;
    }
#pragma unroll
    for (int r = 0; r < NPT; ++r)
        Y[(node0 + threadIdx.y * NPT + r) * FOUT + j] = acc[r];
}

// per-node attention logits: one wave per node, C=64 lanes
template <int H>
__global__ __launch_bounds__(256) void node_alpha(const float* __restrict__ Hbuf,
                                                  const float* __restrict__ a_s,
                                                  const float* __restrict__ a_d,
                                                  float* __restrict__ as_out,
                                                  float* __restrict__ ad_out, int N) {
    int wid = threadIdx.x >> 6, lane = threadIdx.x & 63;
    int n = blockIdx.x * 4 + wid;
    if (n >= N) return;
    const float* hrow = Hbuf + (size_t)n * (H * 64);
#pragma unroll
    for (int h = 0; h < H; ++h) {
        float hv = hrow[h * 64 + lane];
        float ps = hv * a_s[h * 64 + lane];
        float pd = hv * a_d[h * 64 + lane];
#pragma unroll
        for (int off = 32; off; off >>= 1) {
            ps += __shfl_xor(ps, off);
            pd += __shfl_xor(pd, off);
        }
        if (lane == 0) { as_out[n * H + h] = ps; ad_out[n * H + h] = pd; }
    }
}

template <int H>
__global__ __launch_bounds__(256) void edge_max(const int* __restrict__ ei,
                                                const float* __restrict__ as,
                                                const float* __restrict__ ad,
                                                unsigned* __restrict__ m) {
    int e = blockIdx.x * blockDim.x + threadIdx.x;
    if (e >= E_TOTC) return;
    int s, d;
    if (e < N_EDGESC) { s = ei[e]; d = ei[N_EDGESC + e]; } else { s = d = e - N_EDGESC; }
#pragma unroll
    for (int h = 0; h < H; ++h) {
        float v = as[s * H + h] + ad[d * H + h];
        v = v >= 0.f ? v : NEG_SLOPE * v;
        atomicMax(&m[d * H + h], enc_f32(v));
    }
}

// one wave per edge: accumulate exp(e-m)*h[src] into acc[dst], and denom[dst]
template <int H>
__global__ __launch_bounds__(256) void edge_acc(const int* __restrict__ ei,
                                                const float* __restrict__ as,
                                                const float* __restrict__ ad,
                                                const unsigned* __restrict__ m,
                                                const float* __restrict__ Hbuf,
                                                float* __restrict__ acc,
                                                float* __restrict__ denom) {
    int wid = threadIdx.x >> 6, lane = threadIdx.x & 63;
    int e = blockIdx.x * 4 + wid;
    if (e >= E_TOTC) return;
    int s, d;
    if (e < N_EDGESC) { s = ei[e]; d = ei[N_EDGESC + e]; } else { s = d = e - N_EDGESC; }
    float w[H];
#pragma unroll
    for (int h = 0; h < H; ++h) {
        float v = as[s * H + h] + ad[d * H + h];
        v = v >= 0.f ? v : NEG_SLOPE * v;
        w[h] = __expf(v - dec_f32(m[d * H + h]));
    }
    if (lane == 0) {
#pragma unroll
        for (int h = 0; h < H; ++h) atomicAdd(&denom[d * H + h], w[h]);
    }
#pragma unroll
    for (int h = 0; h < H; ++h) {
        float hv = Hbuf[(size_t)s * (H * 64) + h * 64 + lane];
        atomicAdd(&acc[(size_t)d * (H * 64) + h * 64 + lane], w[h] * hv);
    }
}

template <int H, bool RELU>
__global__ __launch_bounds__(256) void finalize(const float* __restrict__ acc,
                                                const float* __restrict__ denom,
                                                const float* __restrict__ b,
                                                float* __restrict__ out, int N) {
    constexpr int HC = H * 64;
    int idx = blockIdx.x * blockDim.x + threadIdx.x;
    if (idx >= N * HC) return;
    int n = idx / HC;
    int col = idx - n * HC;
    int h = col >> 6;
    float v = acc[idx] / fmaxf(denom[n * H + h], 1e-16f) + b[col];
    if (RELU) v = fmaxf(v, 0.f);
    out[idx] = v;
}

__global__ __launch_bounds__(256) void pool_nodes(const float* __restrict__ h2,
                                                  const int* __restrict__ batch,
                                                  float* __restrict__ msum,
                                                  unsigned* __restrict__ mmax,
                                                  float* __restrict__ cnt, int N) {
    int wid = threadIdx.x >> 6, lane = threadIdx.x & 63;
    int n = blockIdx.x * 4 + wid;
    if (n >= N) return;
    int g = batch[n];
    float v = h2[(size_t)n * 64 + lane];
    atomicAdd(&msum[g * 64 + lane], v);
    atomicMax(&mmax[g * 64 + lane], enc_f32(v));
    if (lane == 0) atomicAdd(&cnt[g], 1.0f);
}

__global__ __launch_bounds__(64) void mlp_head(const float* __restrict__ msum,
                                               const unsigned* __restrict__ mmax,
                                               const float* __restrict__ cnt,
                                               const float* __restrict__ Wf1,
                                               const float* __restrict__ bf1,
                                               const float* __restrict__ Wf2,
                                               const float* __restrict__ bf2,
                                               float* __restrict__ out) {
    __shared__ float pooled[128];
    int g = blockIdx.x, lane = threadIdx.x;
    float c = cnt[g];
    pooled[lane] = msum[g * 64 + lane] / fmaxf(c, 1.0f);
    pooled[64 + lane] = (c > 0.f) ? dec_f32(mmax[g * 64 + lane]) : 0.f;
    __syncthreads();
    float acc = bf1[lane];
#pragma unroll
    for (int k = 0; k < 128; ++k) acc += pooled[k] * Wf1[k * 64 + lane];
    acc = fmaxf(acc, 0.f);
    float r = acc * Wf2[lane];
#pragma unroll
    for (int off = 32; off; off >>= 1) r += __shfl_xor(r, off);
    if (lane == 0) out[g] = r + bf2[0];
}

extern "C" void kernel_launch(void* const* d_in, const int* in_sizes, int n_in,
                              void* d_out, int out_size, void* d_ws, size_t ws_size,
                              hipStream_t stream) {
    const float* x    = (const float*)d_in[0];
    const int*   ei   = (const int*)d_in[1];
    const int*   batch= (const int*)d_in[2];
    const float* W1   = (const float*)d_in[3];
    const float* as1  = (const float*)d_in[4];
    const float* ad1  = (const float*)d_in[5];
    const float* b1   = (const float*)d_in[6];
    const float* W2   = (const float*)d_in[7];
    const float* as2  = (const float*)d_in[8];
    const float* ad2  = (const float*)d_in[9];
    const float* b2   = (const float*)d_in[10];
    const float* Wf1  = (const float*)d_in[11];
    const float* bf1  = (const float*)d_in[12];
    const float* Wf2  = (const float*)d_in[13];
    const float* bf2  = (const float*)d_in[14];
    float* out = (float*)d_out;

    const size_t N = N_NODESC;
    float* ws = (float*)d_ws;
    float*    h1   = ws;                  // [N,128]; later h2=[0,N*64), acc2=[N*64,N*128)
    float*    acc1 = ws + N * 128;        // [N,128]; finalized in place -> layer-2 input
    float*    small = ws + 2 * N * 128;
    float*    as1b = small;               // N*2
    float*    ad1b = small + N * 2;       // N*2
    unsigned* m1   = (unsigned*)(small + N * 4);  // N*2
    float*    den1 = small + N * 6;       // N*2
    float*    as2b = small + N * 8;       // N
    float*    ad2b = small + N * 9;       // N
    unsigned* m2   = (unsigned*)(small + N * 10); // N
    float*    den2 = small + N * 11;      // N
    float*    msum = small + N * 12;      // 512*64
    unsigned* mmax = (unsigned*)(small + N * 12 + 512 * 64);
    float*    cntb = small + N * 12 + 2 * 512 * 64; // 512
    float* h2 = h1;
    float* acc2 = h1 + N * 64;

    // init (d_ws is poisoned 0xAA before every call)
    hipMemsetAsync(acc1, 0, N * 128 * 4, stream);
    hipMemsetAsync(den1, 0, N * 2 * 4, stream);
    hipMemsetAsync(den2, 0, N * 4, stream);
    hipMemsetAsync(msum, 0, 512 * 64 * 4, stream);
    hipMemsetAsync(cntb, 0, 512 * 4, stream);
    fill_u32<<<(N * 2 + 255) / 256, 256, 0, stream>>>(m1, NEG_INF_ENC, N * 2);
    fill_u32<<<(N + 255) / 256, 256, 0, stream>>>(m2, NEG_INF_ENC, N);
    fill_u32<<<(512 * 64 + 255) / 256, 256, 0, stream>>>(mmax, NEG_INF_ENC, 512 * 64);

    // ---- layer 1 (H=2) ----
    gemm_rm<128, 8><<<N / 16, dim3(128, 2), 0, stream>>>(x, W1, h1, N);
    node_alpha<2><<<(N + 3) / 4, 256, 0, stream>>>(h1, as1, ad1, as1b, ad1b, N);
    edge_max<2><<<(E_TOTC + 255) / 256, 256, 0, stream>>>(ei, as1b, ad1b, m1);
    edge_acc<2><<<(E_TOTC + 3) / 4, 256, 0, stream>>>(ei, as1b, ad1b, m1, h1, acc1, den1);
    finalize<2, true><<<(N * 128 + 255) / 256, 256, 0, stream>>>(acc1, den1, b1, acc1, N);

    // ---- layer 2 (H=1); h1 is dead now, acc2 overlaps its upper half ----
    hipMemsetAsync(acc2, 0, N * 64 * 4, stream);
    gemm_rm<64, 8><<<N / 32, dim3(64, 4), 0, stream>>>(acc1, W2, h2, N);
    node_alpha<1><<<(N + 3) / 4, 256, 0, stream>>>(h2, as2, ad2, as2b, ad2b, N);
    edge_max<1><<<(E_TOTC + 255) / 256, 256, 0, stream>>>(ei, as2b, ad2b, m2);
    edge_acc<1><<<(E_TOTC + 3) / 4, 256, 0, stream>>>(ei, as2b, ad2b, m2, h2, acc2, den2);
    finalize<1, false><<<(N * 64 + 255) / 256, 256, 0, stream>>>(acc2, den2, b2, acc2, N);

    // ---- pool + MLP ----
    pool_nodes<<<(N + 3) / 4, 256, 0, stream>>>(acc2, batch, msum, mmax, cntb, N);
    mlp_head<<<NUM_GRAPHSC, 64, 0, stream>>>(msum, mmax, cntb, Wf1, bf1, Wf2, bf2, out);
}

// Round 2
// 830.605 us; speedup vs baseline: 1.3803x; 1.3803x over previous
//
#include <hip/hip_runtime.h>

#define N_NODESC 100000
#define N_EDGESC 600000
#define E_TOTC   700000
#define NUM_GRAPHSC 512
#define NEG_SLOPE 0.2f
#define NEG_INF_ENC 0x007FFFFFu

// monotone float<->uint mapping so unsigned atomicMax == float max
__device__ __forceinline__ unsigned enc_f32(float f) {
    unsigned u = __float_as_uint(f);
    return (u & 0x80000000u) ? ~u : (u | 0x80000000u);
}
__device__ __forceinline__ float dec_f32(unsigned u) {
    u = (u & 0x80000000u) ? (u ^ 0x80000000u) : ~u;
    return __uint_as_float(u);
}

__global__ void fill_u32(unsigned* __restrict__ p, unsigned v, int n) {
    int i = blockIdx.x * blockDim.x + threadIdx.x;
    if (i < n) p[i] = v;
}

// ---------------- CSR build (shared by both layers) ----------------
__global__ __launch_bounds__(256) void hist_dst(const int* __restrict__ ei,
                                                int* __restrict__ deg) {
    int e = blockIdx.x * blockDim.x + threadIdx.x;
    if (e < N_EDGESC) atomicAdd(&deg[ei[N_EDGESC + e]], 1);
}

// single-block exclusive scan of deg[0..n) -> off
__global__ __launch_bounds__(1024) void scan_deg(const int* __restrict__ deg,
                                                 int* __restrict__ off, int n) {
    __shared__ int sums[1024];
    int t = threadIdx.x;
    const int CHUNK = (n + 1023) / 1024;
    int lo = t * CHUNK, hi = min(lo + CHUNK, n);
    int s = 0;
    for (int i = lo; i < hi; ++i) s += deg[i];
    sums[t] = s;
    __syncthreads();
    for (int d = 1; d < 1024; d <<= 1) {
        int v = (t >= d) ? sums[t - d] : 0;
        __syncthreads();
        sums[t] += v;
        __syncthreads();
    }
    int run = (t == 0) ? 0 : sums[t - 1];
    for (int i = lo; i < hi; ++i) { off[i] = run; run += deg[i]; }
}

// scatter src ids into CSR slots; off[d] advances from start to end
__global__ __launch_bounds__(256) void scatter_csr(const int* __restrict__ ei,
                                                   int* __restrict__ off,
                                                   int* __restrict__ csr) {
    int e = blockIdx.x * blockDim.x + threadIdx.x;
    if (e >= E_TOTC) return;
    int s, d;
    if (e < N_EDGESC) { s = ei[e]; d = ei[N_EDGESC + e]; } else { s = d = e - N_EDGESC; }
    int slot = atomicAdd(&off[d], 1);
    csr[slot] = s;
}

// ---------------- dense kernels ----------------
// Y[n,j] = sum_k X[n,k] * W[k,j];  K = 128 fixed. blockDim=(FOUT, 256/FOUT)
template <int FOUT, int NPT>
__global__ __launch_bounds__(256) void gemm_rm(const float* __restrict__ X,
                                               const float* __restrict__ W,
                                               float* __restrict__ Y, int N) {
    constexpr int K = 128;
    constexpr int NROWS = 256 / FOUT;
    constexpr int NPB = NROWS * NPT;
    __shared__ float xs[NPB][K];
    int tid = threadIdx.y * FOUT + threadIdx.x;
    size_t node0 = (size_t)blockIdx.x * NPB;
    const float4* Xv = (const float4*)(X + node0 * K);
    float4* xsv = (float4*)(&xs[0][0]);
#pragma unroll
    for (int i = 0; i < NPB * K / 4 / 256; ++i) xsv[tid + i * 256] = Xv[tid + i * 256];
    __syncthreads();
    int j = threadIdx.x;
    float acc[NPT];
#pragma unroll
    for (int r = 0; r < NPT; ++r) acc[r] = 0.f;
    const float* xrow = &xs[threadIdx.y * NPT][0];
#pragma unroll
    for (int k = 0; k < K; ++k) {
        float w = W[k * FOUT + j];
#pragma unroll
        for (int r = 0; r < NPT; ++r) acc[r] += xrow[r * K + k] * w;
    }
#pragma unroll
    for (int r = 0; r < NPT; ++r)
        Y[(node0 + threadIdx.y * NPT + r) * FOUT + j] = acc[r];
}

// per-node attention logits: one wave per node, C=64 lanes
template <int H>
__global__ __launch_bounds__(256) void node_alpha(const float* __restrict__ Hbuf,
                                                  const float* __restrict__ a_s,
                                                  const float* __restrict__ a_d,
                                                  float* __restrict__ as_out,
                                                  float* __restrict__ ad_out, int N) {
    int wid = threadIdx.x >> 6, lane = threadIdx.x & 63;
    int n = blockIdx.x * 4 + wid;
    if (n >= N) return;
    const float* hrow = Hbuf + (size_t)n * (H * 64);
#pragma unroll
    for (int h = 0; h < H; ++h) {
        float hv = hrow[h * 64 + lane];
        float ps = hv * a_s[h * 64 + lane];
        float pd = hv * a_d[h * 64 + lane];
#pragma unroll
        for (int off = 32; off; off >>= 1) {
            ps += __shfl_xor(ps, off);
            pd += __shfl_xor(pd, off);
        }
        if (lane == 0) { as_out[n * H + h] = ps; ad_out[n * H + h] = pd; }
    }
}

// ---------------- fused gather aggregation (max+softmax+weighted sum+bias+relu)
// one wave per destination node; no atomics, h[src] gathers are L3-resident
template <int H, bool RELU>
__global__ __launch_bounds__(256) void gat_gather(const int* __restrict__ off_end,
                                                  const int* __restrict__ deg,
                                                  const int* __restrict__ csr,
                                                  const float* __restrict__ as,
                                                  const float* __restrict__ ad,
                                                  const float* __restrict__ Hbuf,
                                                  const float* __restrict__ b,
                                                  float* __restrict__ out, int N) {
    constexpr int HC = H * 64;
    int wid = threadIdx.x >> 6, lane = threadIdx.x & 63;
    int n = blockIdx.x * 4 + wid;
    if (n >= N) return;
    int dg = deg[n];
    int o = off_end[n] - dg;  // scatter advanced off to end-of-range
    float adv[H];
#pragma unroll
    for (int h = 0; h < H; ++h) adv[h] = ad[n * H + h];

    // pass 1: running max over in-edges (lanes parallel over edges)
    float mx[H];
#pragma unroll
    for (int h = 0; h < H; ++h) mx[h] = -1e30f;
    for (int i = lane; i < dg; i += 64) {
        int s = csr[o + i];
#pragma unroll
        for (int h = 0; h < H; ++h) {
            float v = as[s * H + h] + adv[h];
            v = v >= 0.f ? v : NEG_SLOPE * v;
            mx[h] = fmaxf(mx[h], v);
        }
    }
#pragma unroll
    for (int h = 0; h < H; ++h)
#pragma unroll
        for (int sh = 32; sh; sh >>= 1) mx[h] = fmaxf(mx[h], __shfl_xor(mx[h], sh));

    // pass 2: chunk of 64 edges -> per-lane weight, then broadcast via shfl
    float acc[H], den[H];
#pragma unroll
    for (int h = 0; h < H; ++h) { acc[h] = 0.f; den[h] = 0.f; }
    for (int base = 0; base < dg; base += 64) {
        int i = base + lane;
        int s = 0;
        float w[H];
#pragma unroll
        for (int h = 0; h < H; ++h) w[h] = 0.f;
        if (i < dg) {
            s = csr[o + i];
#pragma unroll
            for (int h = 0; h < H; ++h) {
                float v = as[s * H + h] + adv[h];
                v = v >= 0.f ? v : NEG_SLOPE * v;
                w[h] = __expf(v - mx[h]);
                den[h] += w[h];
            }
        }
        int cnt = min(dg - base, 64);
        for (int j = 0; j < cnt; ++j) {
            int sj = __shfl(s, j);
#pragma unroll
            for (int h = 0; h < H; ++h) {
                float wj = __shfl(w[h], j);
                acc[h] += wj * Hbuf[(size_t)sj * HC + h * 64 + lane];
            }
        }
    }
#pragma unroll
    for (int h = 0; h < H; ++h) {
#pragma unroll
        for (int sh = 32; sh; sh >>= 1) den[h] += __shfl_xor(den[h], sh);
        float v = acc[h] / fmaxf(den[h], 1e-16f) + b[h * 64 + lane];
        if (RELU) v = fmaxf(v, 0.f);
        out[(size_t)n * HC + h * 64 + lane] = v;
    }
}

// ---------------- pooling + MLP head ----------------
__global__ __launch_bounds__(256) void pool_nodes(const float* __restrict__ h2,
                                                  const int* __restrict__ batch,
                                                  float* __restrict__ msum,
                                                  unsigned* __restrict__ mmax,
                                                  float* __restrict__ cnt, int N) {
    int wid = threadIdx.x >> 6, lane = threadIdx.x & 63;
    int n = blockIdx.x * 4 + wid;
    if (n >= N) return;
    int g = batch[n];
    float v = h2[(size_t)n * 64 + lane];
    atomicAdd(&msum[g * 64 + lane], v);
    atomicMax(&mmax[g * 64 + lane], enc_f32(v));
    if (lane == 0) atomicAdd(&cnt[g], 1.0f);
}

__global__ __launch_bounds__(64) void mlp_head(const float* __restrict__ msum,
                                               const unsigned* __restrict__ mmax,
                                               const float* __restrict__ cnt,
                                               const float* __restrict__ Wf1,
                                               const float* __restrict__ bf1,
                                               const float* __restrict__ Wf2,
                                               const float* __restrict__ bf2,
                                               float* __restrict__ out) {
    __shared__ float pooled[128];
    int g = blockIdx.x, lane = threadIdx.x;
    float c = cnt[g];
    pooled[lane] = msum[g * 64 + lane] / fmaxf(c, 1.0f);
    pooled[64 + lane] = (c > 0.f) ? dec_f32(mmax[g * 64 + lane]) : 0.f;
    __syncthreads();
    float acc = bf1[lane];
#pragma unroll
    for (int k = 0; k < 128; ++k) acc += pooled[k] * Wf1[k * 64 + lane];
    acc = fmaxf(acc, 0.f);
    float r = acc * Wf2[lane];
#pragma unroll
    for (int off = 32; off; off >>= 1) r += __shfl_xor(r, off);
    if (lane == 0) out[g] = r + bf2[0];
}

extern "C" void kernel_launch(void* const* d_in, const int* in_sizes, int n_in,
                              void* d_out, int out_size, void* d_ws, size_t ws_size,
                              hipStream_t stream) {
    const float* x    = (const float*)d_in[0];
    const int*   ei   = (const int*)d_in[1];
    const int*   batch= (const int*)d_in[2];
    const float* W1   = (const float*)d_in[3];
    const float* as1  = (const float*)d_in[4];
    const float* ad1  = (const float*)d_in[5];
    const float* b1   = (const float*)d_in[6];
    const float* W2   = (const float*)d_in[7];
    const float* as2  = (const float*)d_in[8];
    const float* ad2  = (const float*)d_in[9];
    const float* b2   = (const float*)d_in[10];
    const float* Wf1  = (const float*)d_in[11];
    const float* bf1  = (const float*)d_in[12];
    const float* Wf2  = (const float*)d_in[13];
    const float* bf2  = (const float*)d_in[14];
    float* out = (float*)d_out;

    const size_t N = N_NODESC;
    float* ws = (float*)d_ws;
    float* h1   = ws;            // [N,128] layer1; layer2: h2=[0,N*64), out2=[N*64,N*128)
    float* out1 = ws + N * 128;  // [N,128] layer1 output (layer2 GEMM input)
    float* small = ws + 2 * N * 128;
    float*    as1b = small;                    // 2N
    float*    ad1b = small + 2 * N;            // 2N
    float*    as2b = small + 4 * N;            // N
    float*    ad2b = small + 5 * N;            // N
    float*    msum = small + 6 * N;            // 512*64
    unsigned* mmax = (unsigned*)(small + 6 * N + 512 * 64);
    float*    cntb = small + 6 * N + 2 * 512 * 64;  // 512
    int* ip  = (int*)(small + 6 * N + 2 * 512 * 64 + 512);
    int* deg = ip;          // N
    int* off = ip + N;      // N (start offsets; scatter advances to end)
    int* csr = ip + 2 * N;  // E_TOT src ids
    float* h2   = h1;
    float* out2 = h1 + N * 64;

    // init
    hipMemsetAsync(msum, 0, 512 * 64 * 4, stream);
    hipMemsetAsync(cntb, 0, 512 * 4, stream);
    fill_u32<<<(512 * 64 + 255) / 256, 256, 0, stream>>>(mmax, NEG_INF_ENC, 512 * 64);
    fill_u32<<<(N + 255) / 256, 256, 0, stream>>>((unsigned*)deg, 1u, N);  // self-loop

    // CSR build (reused by both layers)
    hist_dst<<<(N_EDGESC + 255) / 256, 256, 0, stream>>>(ei, deg);
    scan_deg<<<1, 1024, 0, stream>>>(deg, off, N);
    scatter_csr<<<(E_TOTC + 255) / 256, 256, 0, stream>>>(ei, off, csr);

    // ---- layer 1 (H=2) ----
    gemm_rm<128, 8><<<N / 16, dim3(128, 2), 0, stream>>>(x, W1, h1, N);
    node_alpha<2><<<(N + 3) / 4, 256, 0, stream>>>(h1, as1, ad1, as1b, ad1b, N);
    gat_gather<2, true><<<(N + 3) / 4, 256, 0, stream>>>(off, deg, csr, as1b, ad1b,
                                                         h1, b1, out1, N);

    // ---- layer 2 (H=1) ----
    gemm_rm<64, 8><<<N / 32, dim3(64, 4), 0, stream>>>(out1, W2, h2, N);
    node_alpha<1><<<(N + 3) / 4, 256, 0, stream>>>(h2, as2, ad2, as2b, ad2b, N);
    gat_gather<1, false><<<(N + 3) / 4, 256, 0, stream>>>(off, deg, csr, as2b, ad2b,
                                                          h2, b2, out2, N);

    // ---- pool + MLP ----
    pool_nodes<<<(N + 3) / 4, 256, 0, stream>>>(out2, batch, msum, mmax, cntb, N);
    mlp_head<<<NUM_GRAPHSC, 64, 0, stream>>>(msum, mmax, cntb, Wf1, bf1, Wf2, bf2, out);
}